// Round 5
// baseline (150.399 us; speedup 1.0000x reference)
//
#include <hip/hip_runtime.h>

#define BN 8192      // B*N
#define NP 1024      // N
#define NF 64        // F_OUT
#define NSEG 8192
#define CAP 256      // bucket capacity (deg ~ Poisson(128); P(>256) ~ 1e-8/seg)
#define OVF_MAX 4096
#define SOVF 64

typedef float f32x4 __attribute__((ext_vector_type(4)));

// Fused: blocks [0,nsb) bucket-scatter edges (nt-stores); [nsb,..) dual-MLP.
__global__ __launch_bounds__(256) void prep_kernel(
    const float* __restrict__ x,
    const float* __restrict__ W1, const float* __restrict__ b1,
    const float* __restrict__ W2, const float* __restrict__ b2,
    const float* __restrict__ Ws1, const float* __restrict__ bs1,
    const float* __restrict__ Ws2, const float* __restrict__ bs2,
    const int* __restrict__ eb, const int* __restrict__ ei,
    const int* __restrict__ ej, const int* __restrict__ ek,
    int* __restrict__ cursor, int2* __restrict__ rec,
    int* __restrict__ ovf_cnt, int4* __restrict__ ovf,
    float* __restrict__ x1, float* __restrict__ out,
    int nnz, int nsb)
{
    if ((int)blockIdx.x < nsb) {
        const int e0 = (blockIdx.x * 256 + threadIdx.x) * 4;
        if (e0 < nnz) {
            const int4 b4 = *(const int4*)(eb + e0);
            const int4 i4 = *(const int4*)(ei + e0);
            const int4 j4 = *(const int4*)(ej + e0);
            const int4 k4 = *(const int4*)(ek + e0);
            const int bs[4] = {b4.x, b4.y, b4.z, b4.w};
            const int is[4] = {i4.x, i4.y, i4.z, i4.w};
            const int js[4] = {j4.x, j4.y, j4.z, j4.w};
            const int ks[4] = {k4.x, k4.y, k4.z, k4.w};
            #pragma unroll
            for (int c = 0; c < 4; ++c) {
                const int seg = bs[c] * NP + is[c];
                const int pos = atomicAdd(&cursor[seg], 1);
                const int jk = (js[c] << 10) | ks[c];
                if (pos < CAP) {
                    const unsigned long long v =
                        ((unsigned long long)(unsigned)jk << 32) | (unsigned)(e0 + c);
                    __builtin_nontemporal_store(
                        v, (unsigned long long*)(rec + (size_t)seg * CAP + pos));
                } else {
                    const int o = atomicAdd(ovf_cnt, 1);
                    if (o < OVF_MAX) ovf[o] = make_int4(seg, e0 + c, jk, 0);
                }
            }
        }
    } else {
        // dual MLP: one wave per row, shfl broadcasts, no barriers
        const int row = ((int)blockIdx.x - nsb) * 4 + (threadIdx.x >> 6);
        const int t = threadIdx.x & 63;
        const float xv = x[(size_t)row * NF + t];
        float a1 = b1[t], a2 = bs1[t];
        #pragma unroll 8
        for (int c = 0; c < NF; ++c) {
            const float xc = __shfl(xv, c);
            a1 = fmaf(xc, W1[c * NF + t], a1);
            a2 = fmaf(xc, Ws1[c * NF + t], a2);
        }
        const float h1 = fmaxf(a1, 0.f), h2 = fmaxf(a2, 0.f);
        float o1 = b2[t], o2 = bs2[t];
        #pragma unroll 8
        for (int c = 0; c < NF; ++c) {
            o1 = fmaf(__shfl(h1, c), W2[c * NF + t], o1);
            o2 = fmaf(__shfl(h2, c), Ws2[c * NF + t], o2);
        }
        x1[(size_t)row * NF + t]  = fmaxf(o1, 0.f);
        out[(size_t)row * NF + t] = fmaxf(o2, 0.f);
    }
}

// One block per segment. 16 groups of 16 lanes; group owns edge (it+g);
// uniform trip count with zero-scale masking (pads staged as {0,0}).
__global__ __launch_bounds__(256) void gather_kernel(
    const f32x4* __restrict__ Wv4, const f32x4* __restrict__ x14,
    const int* __restrict__ cursor, const int2* __restrict__ rec,
    const int* __restrict__ ovf_cnt, const int4* __restrict__ ovf,
    f32x4* __restrict__ out4)
{
    const int seg = blockIdx.x;
    const int b = seg >> 10;
    const int dtrue = cursor[seg];
    const int cnt = min(dtrue, CAP);

    __shared__ int2 srec[CAP];
    __shared__ int2 sovf[SOVF];
    __shared__ int sovf_n;

    if (threadIdx.x == 0) sovf_n = 0;
    srec[threadIdx.x] = ((int)threadIdx.x < cnt)
        ? rec[(size_t)seg * CAP + threadIdx.x] : make_int2(0, 0);
    __syncthreads();

    const int novf = min(ovf_cnt[0], OVF_MAX);
    if (novf > 0) {   // dead path in practice; exactness guarantee
        for (int o = threadIdx.x; o < novf; o += 256) {
            const int4 r = ovf[o];
            if (r.x == seg) {
                const int p = atomicAdd(&sovf_n, 1);
                if (p < SOVF) sovf[p] = make_int2(r.y, r.z);
            }
        }
        __syncthreads();
    }

    const int g   = threadIdx.x >> 4;
    const int c16 = threadIdx.x & 15;
    const f32x4* __restrict__ x1b = x14 + ((size_t)b << 10) * 16;

    f32x4 acc0 = {0.f, 0.f, 0.f, 0.f}, acc1 = {0.f, 0.f, 0.f, 0.f};
    #pragma unroll 2
    for (int it = 0; it < cnt; it += 32) {
        const int i0 = it + g;
        const int i1 = it + 16 + g;
        const int2 r0 = srec[i0];
        const int2 r1 = srec[i1];
        const float m0 = (i0 < cnt) ? 1.f : 0.f;
        const float m1 = (i1 < cnt) ? 1.f : 0.f;
        const int j0 = r0.y >> 10, k0 = r0.y & 1023;
        const int j1 = r1.y >> 10, k1 = r1.y & 1023;
        const f32x4 w0  = __builtin_nontemporal_load(Wv4 + (size_t)(unsigned)r0.x * 16 + c16);
        const f32x4 w1  = __builtin_nontemporal_load(Wv4 + (size_t)(unsigned)r1.x * 16 + c16);
        const f32x4 xj0 = x1b[j0 * 16 + c16];
        const f32x4 xk0 = x1b[k0 * 16 + c16];
        const f32x4 xj1 = x1b[j1 * 16 + c16];
        const f32x4 xk1 = x1b[k1 * 16 + c16];
        acc0 += (m0 * w0) * (xj0 * xk0);
        acc1 += (m1 * w1) * (xj1 * xk1);
    }

    if (sovf_n > 0) {   // overflow contributions (practically never taken)
        const int nov = min(sovf_n, SOVF);
        for (int it = 0; it < nov; it += 16) {
            const int idx = it + g;
            if (idx < nov) {
                const int2 r = sovf[idx];
                const int j = r.y >> 10, k = r.y & 1023;
                const f32x4 w = Wv4[(size_t)(unsigned)r.x * 16 + c16];
                acc0 += w * (x1b[j * 16 + c16] * x1b[k * 16 + c16]);
            }
        }
    }

    f32x4 acc = acc0 + acc1;
    #pragma unroll
    for (int m = 16; m < 64; m <<= 1) {
        acc.x += __shfl_xor(acc.x, m);
        acc.y += __shfl_xor(acc.y, m);
        acc.z += __shfl_xor(acc.z, m);
        acc.w += __shfl_xor(acc.w, m);
    }

    __shared__ f32x4 sm[4][16];
    const int wave = threadIdx.x >> 6;
    const int lane = threadIdx.x & 63;
    if ((lane >> 4) == 0) sm[wave][c16] = acc;
    __syncthreads();
    if (threadIdx.x < 16) {
        const f32x4 s = (sm[0][c16] + sm[1][c16]) + (sm[2][c16] + sm[3][c16]);
        const float a = 1.0f / ((float)dtrue + 1e-10f);
        f32x4 o = out4[(size_t)seg * 16 + c16];
        o += a * s;
        out4[(size_t)seg * 16 + c16] = o;
    }
}

extern "C" void kernel_launch(void* const* d_in, const int* in_sizes, int n_in,
                              void* d_out, int out_size, void* d_ws, size_t ws_size,
                              hipStream_t stream) {
    const float* x   = (const float*)d_in[0];
    const float* Wv  = (const float*)d_in[1];
    const int*   eb  = (const int*)d_in[2];
    const int*   ei  = (const int*)d_in[3];
    const int*   ej  = (const int*)d_in[4];
    const int*   ek  = (const int*)d_in[5];
    const float* W1  = (const float*)d_in[6];
    const float* b1  = (const float*)d_in[7];
    const float* W2  = (const float*)d_in[8];
    const float* b2  = (const float*)d_in[9];
    const float* Ws1 = (const float*)d_in[10];
    const float* bs1 = (const float*)d_in[11];
    const float* Ws2 = (const float*)d_in[12];
    const float* bs2 = (const float*)d_in[13];
    float* out = (float*)d_out;
    const int nnz = in_sizes[2];

    char* ws = (char*)d_ws;
    float* x1    = (float*)ws;                             // 2 MB
    int* cursor  = (int*)(ws + (2 << 20));                 // 32 KB (doubles as degree)
    int* ovf_cnt = cursor + NSEG;                          // 4 B (contiguous w/ cursor)
    int4* ovf    = (int4*)(ws + (2 << 20) + (64 << 10));   // 64 KB
    int2* rec    = (int2*)(ws + (2 << 20) + (128 << 10));  // 16 MB

    const int nsb = nnz / 1024;    // scatter blocks: 256 thr × 4 edges
    const int nmlp = BN / 4;       // MLP blocks: 4 waves × 1 row

    hipMemsetAsync(cursor, 0, (NSEG + 1) * sizeof(int), stream);
    prep_kernel<<<nsb + nmlp, 256, 0, stream>>>(x, W1, b1, W2, b2, Ws1, bs1, Ws2, bs2,
                                                eb, ei, ej, ek, cursor, rec, ovf_cnt, ovf,
                                                x1, out, nnz, nsb);
    gather_kernel<<<NSEG, 256, 0, stream>>>((const f32x4*)Wv, (const f32x4*)x1,
                                            cursor, rec, ovf_cnt, ovf, (f32x4*)out);
}

// Round 6
// 146.213 us; speedup vs baseline: 1.0286x; 1.0286x over previous
//
#include <hip/hip_runtime.h>

#define BN 8192      // B*N
#define NP 1024      // N
#define NF 64        // F_OUT
#define NSEG 8192
#define CAP 256      // bucket capacity (deg ~ Poisson(128); P(>256) ~ 1e-8/seg)
#define OVF_MAX 4096
#define EMASK 0xFFFFF   // nnz = 2^20 exactly (harness-fixed)

typedef float f32x4 __attribute__((ext_vector_type(4)));

// Fused: blocks [0,nsb) bucket-scatter edges; [nsb,..) dual-MLP (wave/row, shfl bcast)
__global__ __launch_bounds__(256) void prep_kernel(
    const float* __restrict__ x,
    const float* __restrict__ W1, const float* __restrict__ b1,
    const float* __restrict__ W2, const float* __restrict__ b2,
    const float* __restrict__ Ws1, const float* __restrict__ bs1,
    const float* __restrict__ Ws2, const float* __restrict__ bs2,
    const int* __restrict__ eb, const int* __restrict__ ei,
    const int* __restrict__ ej, const int* __restrict__ ek,
    int* __restrict__ cursor, int2* __restrict__ rec,
    int* __restrict__ ovf_cnt, int4* __restrict__ ovf,
    float* __restrict__ x1, float* __restrict__ out,
    int nnz, int nsb)
{
    if ((int)blockIdx.x < nsb) {
        const int e0 = (blockIdx.x * 256 + threadIdx.x) * 4;
        if (e0 < nnz) {
            const int4 b4 = *(const int4*)(eb + e0);
            const int4 i4 = *(const int4*)(ei + e0);
            const int4 j4 = *(const int4*)(ej + e0);
            const int4 k4 = *(const int4*)(ek + e0);
            const int bs[4] = {b4.x, b4.y, b4.z, b4.w};
            const int is[4] = {i4.x, i4.y, i4.z, i4.w};
            const int js[4] = {j4.x, j4.y, j4.z, j4.w};
            const int ks[4] = {k4.x, k4.y, k4.z, k4.w};
            #pragma unroll
            for (int c = 0; c < 4; ++c) {
                const int seg = bs[c] * NP + is[c];
                const int pos = atomicAdd(&cursor[seg], 1);
                const int jk = (js[c] << 10) | ks[c];
                if (pos < CAP) {
                    rec[(size_t)seg * CAP + pos] = make_int2(e0 + c, jk);
                } else {
                    const int o = atomicAdd(ovf_cnt, 1);
                    if (o < OVF_MAX) ovf[o] = make_int4(seg, e0 + c, jk, 0);
                }
            }
        }
    } else {
        // dual MLP: one wave per row, shfl broadcasts, no barriers
        const int row = ((int)blockIdx.x - nsb) * 4 + (threadIdx.x >> 6);
        const int t = threadIdx.x & 63;
        const float xv = x[(size_t)row * NF + t];
        float a1 = b1[t], a2 = bs1[t];
        #pragma unroll 8
        for (int c = 0; c < NF; ++c) {
            const float xc = __shfl(xv, c);
            a1 = fmaf(xc, W1[c * NF + t], a1);
            a2 = fmaf(xc, Ws1[c * NF + t], a2);
        }
        const float h1 = fmaxf(a1, 0.f), h2 = fmaxf(a2, 0.f);
        float o1 = b2[t], o2 = bs2[t];
        #pragma unroll 8
        for (int c = 0; c < NF; ++c) {
            o1 = fmaf(__shfl(h1, c), W2[c * NF + t], o1);
            o2 = fmaf(__shfl(h2, c), Ws2[c * NF + t], o2);
        }
        x1[(size_t)row * NF + t]  = fmaxf(o1, 0.f);
        out[(size_t)row * NF + t] = fmaxf(o2, 0.f);
    }
}

// Wave-per-segment gather: 4 independent waves per block, NO barriers.
// Each wave stages its seg's records to LDS, 16-lane groups own edges,
// pure shfl reduction, 16 lanes RMW the output.
__global__ __launch_bounds__(256) void gather_kernel(
    const f32x4* __restrict__ Wv4, const f32x4* __restrict__ x14,
    const int* __restrict__ cursor, const int2* __restrict__ rec,
    f32x4* __restrict__ out4)
{
    __shared__ int2 srec[4][CAP];
    const int w    = threadIdx.x >> 6;
    const int lane = threadIdx.x & 63;
    const int seg  = blockIdx.x * 4 + w;
    const int b    = seg >> 10;
    const int dtrue = cursor[seg];
    const int cnt  = min(dtrue, CAP);

    // coalesced stage of this wave's bucket (same-wave LDS dep: no barrier)
    for (int i = lane; i < cnt; i += 64)
        srec[w][i] = rec[(size_t)seg * CAP + i];

    const int sub = lane >> 4;
    const int c16 = lane & 15;
    const f32x4* __restrict__ x1b = x14 + ((size_t)b << 10) * 16;

    f32x4 acc = {0.f, 0.f, 0.f, 0.f};
    #pragma unroll 2
    for (int it = 0; it < cnt; it += 4) {
        int idx = it + sub;
        const float m = (idx < cnt) ? 1.f : 0.f;
        idx = min(idx, cnt - 1);                 // tail clamp (cnt>0 here)
        const int2 r = srec[w][idx];
        const int e = r.x & EMASK;               // safe even on clamped lanes
        const int j = (r.y >> 10) & 1023, k = r.y & 1023;
        const f32x4 wv = __builtin_nontemporal_load(Wv4 + (size_t)e * 16 + c16);
        const f32x4 xj = x1b[j * 16 + c16];
        const f32x4 xk = x1b[k * 16 + c16];
        acc += (m * wv) * (xj * xk);
    }

    // combine the 4 sub-groups (lanes ^16, ^32)
    #pragma unroll
    for (int mm = 16; mm < 64; mm <<= 1) {
        acc.x += __shfl_xor(acc.x, mm);
        acc.y += __shfl_xor(acc.y, mm);
        acc.z += __shfl_xor(acc.z, mm);
        acc.w += __shfl_xor(acc.w, mm);
    }

    if (sub == 0) {
        const float a = 1.0f / ((float)dtrue + 1e-10f);
        f32x4 o = out4[(size_t)seg * 16 + c16];
        out4[(size_t)seg * 16 + c16] = o + a * acc;
    }
}

// Exact handling of bucket overflow (expected count: 0); runs after gather.
__global__ void cleanup_kernel(const float* __restrict__ Wv, const float* __restrict__ x1,
                               const int* __restrict__ cursor, const int* __restrict__ ovf_cnt,
                               const int4* __restrict__ ovf, float* __restrict__ out)
{
    const int n = min(*ovf_cnt, OVF_MAX);
    const int wid = (blockIdx.x * blockDim.x + threadIdx.x) >> 6;
    const int lane = threadIdx.x & 63;
    const int nw = (gridDim.x * blockDim.x) >> 6;
    for (int o = wid; o < n; o += nw) {
        const int4 r = ovf[o];
        const int seg = r.x, e = r.y, j = r.z >> 10, k = r.z & 1023, b = seg >> 10;
        const float a = 1.0f / ((float)cursor[seg] + 1e-10f);
        atomicAdd(&out[(size_t)seg * NF + lane],
                  a * Wv[(size_t)e * NF + lane]
                    * x1[((size_t)(b << 10) + j) * NF + lane]
                    * x1[((size_t)(b << 10) + k) * NF + lane]);
    }
}

extern "C" void kernel_launch(void* const* d_in, const int* in_sizes, int n_in,
                              void* d_out, int out_size, void* d_ws, size_t ws_size,
                              hipStream_t stream) {
    const float* x   = (const float*)d_in[0];
    const float* Wv  = (const float*)d_in[1];
    const int*   eb  = (const int*)d_in[2];
    const int*   ei  = (const int*)d_in[3];
    const int*   ej  = (const int*)d_in[4];
    const int*   ek  = (const int*)d_in[5];
    const float* W1  = (const float*)d_in[6];
    const float* b1  = (const float*)d_in[7];
    const float* W2  = (const float*)d_in[8];
    const float* b2  = (const float*)d_in[9];
    const float* Ws1 = (const float*)d_in[10];
    const float* bs1 = (const float*)d_in[11];
    const float* Ws2 = (const float*)d_in[12];
    const float* bs2 = (const float*)d_in[13];
    float* out = (float*)d_out;
    const int nnz = in_sizes[2];

    char* ws = (char*)d_ws;
    float* x1    = (float*)ws;                             // 2 MB
    int* cursor  = (int*)(ws + (2 << 20));                 // 32 KB (doubles as degree)
    int* ovf_cnt = cursor + NSEG;                          // 4 B
    int4* ovf    = (int4*)(ws + (2 << 20) + (64 << 10));   // 64 KB
    int2* rec    = (int2*)(ws + (2 << 20) + (128 << 10));  // 16 MB

    const int nsb = nnz / 1024;    // scatter blocks: 256 thr × 4 edges
    const int nmlp = BN / 4;       // MLP blocks: 4 waves × 1 row

    hipMemsetAsync(cursor, 0, (NSEG + 1) * sizeof(int), stream);
    prep_kernel<<<nsb + nmlp, 256, 0, stream>>>(x, W1, b1, W2, b2, Ws1, bs1, Ws2, bs2,
                                                eb, ei, ej, ek, cursor, rec, ovf_cnt, ovf,
                                                x1, out, nnz, nsb);
    gather_kernel<<<NSEG / 4, 256, 0, stream>>>((const f32x4*)Wv, (const f32x4*)x1,
                                                cursor, rec, (f32x4*)out);
    cleanup_kernel<<<16, 256, 0, stream>>>(Wv, x1, cursor, ovf_cnt, ovf, out);
}